// Round 1
// baseline (137.029 us; speedup 1.0000x reference)
//
#include <hip/hip_runtime.h>
#include <hip/hip_bf16.h>
#include <math.h>

// D[k][n] = 0.5*cos(pi*(2n+1)k/16), row 0 scaled by 1/sqrt(2).
__device__ __forceinline__ float dctD(int k, int n) {
    const float c[9] = {1.0f, 0.98078528040323043f, 0.92387953251128674f,
                        0.83146961230254524f, 0.70710678118654752f,
                        0.55557023301960218f, 0.38268343236508977f,
                        0.19509032201612825f, 0.0f};
    int m = ((2 * n + 1) * k) & 31;   // cos(m*pi/16), periodic 32
    float s = 1.0f;
    if (m > 16) m = 32 - m;
    if (m > 8) { m = 16 - m; s = -1.0f; }
    float scale = (k == 0) ? 0.35355339059327373f : 0.5f;
    return scale * s * c[m];
}

__device__ __forceinline__ float sigmoidf(float a) {
    return 1.0f / (1.0f + expf(-a));
}

// Workspace layout (floats):
//   feat   : [0, 65536)    feat[f*1024 + br*32 + bc]
//   scale_c: [65536, 65600)
//   out2d  : [65600, 131136)
#define WS_FEAT    0
#define WS_SCALEC  65536
#define WS_OUT2D   65600

// 1024 threads total: thread t = br*32+bc handles block (br, bc).
__global__ void dct_kernel(const float* __restrict__ x, float* __restrict__ feat) {
    __shared__ float Ds[64];
    int tid = threadIdx.x;
    if (tid < 64) Ds[tid] = dctD(tid >> 3, tid & 7);
    __syncthreads();
    int t = blockIdx.x * blockDim.x + tid;   // 0..1023
    int br = t >> 5, bc = t & 31;

    float blk[8][8];
    #pragma unroll
    for (int k = 0; k < 8; k++) {
        int row = br * 8 + k;
        #pragma unroll
        for (int l = 0; l < 8; l++) {
            blk[k][l] = x[(row * 256 + bc * 8 + l) * 3];   // channel 0
        }
    }
    // tmp[i][l] = sum_k D[i][k] * blk[k][l]
    float tmp[8][8];
    #pragma unroll
    for (int i = 0; i < 8; i++) {
        #pragma unroll
        for (int l = 0; l < 8; l++) {
            float s = 0.f;
            #pragma unroll
            for (int k = 0; k < 8; k++) s += Ds[i * 8 + k] * blk[k][l];
            tmp[i][l] = s;
        }
    }
    // dct[i][j] = sum_l tmp[i][l] * D[j][l]
    #pragma unroll
    for (int i = 0; i < 8; i++) {
        #pragma unroll
        for (int j = 0; j < 8; j++) {
            float s = 0.f;
            #pragma unroll
            for (int l = 0; l < 8; l++) s += tmp[i][l] * Ds[j * 8 + l];
            feat[(i * 8 + j) * 1024 + t] = s;   // coalesced across t
        }
    }
}

// One workgroup of 256 threads: channel means -> fc1(relu) -> fc2(sigmoid) -> scale_c.
__global__ void se_kernel(const float* __restrict__ feat,
                          const float* __restrict__ fc1_w, const float* __restrict__ fc1_b,
                          const float* __restrict__ fc2_w, const float* __restrict__ fc2_b,
                          float* __restrict__ scale_c) {
    __shared__ float partial[256];
    __shared__ float sq[64];
    __shared__ float h[32];
    int tid = threadIdx.x;
    int c = tid >> 2, q = tid & 3;
    const float4* f4 = (const float4*)(feat + c * 1024 + q * 256);
    float s = 0.f;
    #pragma unroll 4
    for (int i = 0; i < 64; i++) { float4 v = f4[i]; s += v.x + v.y + v.z + v.w; }
    partial[tid] = s;
    __syncthreads();
    if (tid < 64) {
        sq[tid] = (partial[tid * 4] + partial[tid * 4 + 1] +
                   partial[tid * 4 + 2] + partial[tid * 4 + 3]) * (1.0f / 1024.0f);
    }
    __syncthreads();
    if (tid < 32) {
        float a = fc1_b[tid];
        for (int cc = 0; cc < 64; cc++) a += sq[cc] * fc1_w[tid * 64 + cc];
        h[tid] = fmaxf(a, 0.f);
    }
    __syncthreads();
    if (tid < 64) {
        float a = fc2_b[tid];
        for (int r = 0; r < 32; r++) a += h[r] * fc2_w[tid * 32 + r];
        scale_c[tid] = sigmoidf(a);
    }
}

// 1024 threads: per block, fuse spatial sigmoid, y = max(feat*sc, feat*sp), IDCT, write out2d.
__global__ void idct_kernel(const float* __restrict__ feat,
                            const float* __restrict__ scale_c,
                            const float* __restrict__ sse_w,
                            const float* __restrict__ sse_b,
                            float* __restrict__ out2d) {
    __shared__ float Ds[64], sc[64], sw[64];
    int tid = threadIdx.x;
    if (tid < 64) {
        Ds[tid] = dctD(tid >> 3, tid & 7);
        sc[tid] = scale_c[tid];
        sw[tid] = sse_w[tid];
    }
    __syncthreads();
    int t = blockIdx.x * blockDim.x + tid;   // 0..1023
    int br = t >> 5, bc = t & 31;

    float g[64];
    float sdot = sse_b[0];
    #pragma unroll
    for (int f = 0; f < 64; f++) {
        g[f] = feat[f * 1024 + t];           // coalesced
        sdot += sw[f] * g[f];
    }
    float sp = sigmoidf(sdot);
    #pragma unroll
    for (int f = 0; f < 64; f++) {
        g[f] = fmaxf(g[f] * sc[f], g[f] * sp);   // y (feat may be negative!)
    }
    // tmp[k][j] = sum_l y[k][l] * D[l][j]
    float tmp[64];
    #pragma unroll
    for (int k = 0; k < 8; k++) {
        #pragma unroll
        for (int j = 0; j < 8; j++) {
            float s = 0.f;
            #pragma unroll
            for (int l = 0; l < 8; l++) s += g[k * 8 + l] * Ds[l * 8 + j];
            tmp[k * 8 + j] = s;
        }
    }
    // idct[i][j] = sum_k D[k][i] * tmp[k][j]; write 8 floats per row (2x float4)
    #pragma unroll
    for (int i = 0; i < 8; i++) {
        float o[8];
        #pragma unroll
        for (int j = 0; j < 8; j++) {
            float s = 0.f;
            #pragma unroll
            for (int k = 0; k < 8; k++) s += Ds[k * 8 + i] * tmp[k * 8 + j];
            o[j] = s;
        }
        float4* dst = (float4*)(out2d + (br * 8 + i) * 256 + bc * 8);
        dst[0] = make_float4(o[0], o[1], o[2], o[3]);
        dst[1] = make_float4(o[4], o[5], o[6], o[7]);
    }
}

// Broadcast out2d (256x256) to all bs*3 = out_size/65536 images. Coalesced float4.
__global__ void bcast_kernel(const float* __restrict__ out2d,
                             float* __restrict__ out, int total4) {
    const float4* s = (const float4*)out2d;
    float4* d = (float4*)out;
    int stride = gridDim.x * blockDim.x;
    for (int idx = blockIdx.x * blockDim.x + threadIdx.x; idx < total4; idx += stride) {
        d[idx] = s[idx & 16383];   // 16384 float4 per 256x256 image
    }
}

extern "C" void kernel_launch(void* const* d_in, const int* in_sizes, int n_in,
                              void* d_out, int out_size, void* d_ws, size_t ws_size,
                              hipStream_t stream) {
    const float* x     = (const float*)d_in[0];
    const float* fc1_w = (const float*)d_in[1];
    const float* fc1_b = (const float*)d_in[2];
    const float* fc2_w = (const float*)d_in[3];
    const float* fc2_b = (const float*)d_in[4];
    const float* sse_w = (const float*)d_in[5];
    const float* sse_b = (const float*)d_in[6];
    float* ws = (float*)d_ws;
    float* feat    = ws + WS_FEAT;
    float* scale_c = ws + WS_SCALEC;
    float* out2d   = ws + WS_OUT2D;
    float* out = (float*)d_out;

    dct_kernel<<<16, 64, 0, stream>>>(x, feat);
    se_kernel<<<1, 256, 0, stream>>>(feat, fc1_w, fc1_b, fc2_w, fc2_b, scale_c);
    idct_kernel<<<16, 64, 0, stream>>>(feat, scale_c, sse_w, sse_b, out2d);
    int total4 = out_size / 4;
    bcast_kernel<<<3072, 256, 0, stream>>>(out2d, out, total4);
}

// Round 2
// 93.228 us; speedup vs baseline: 1.4698x; 1.4698x over previous
//
#include <hip/hip_runtime.h>
#include <hip/hip_bf16.h>
#include <math.h>

// D[k][n] = 0.5*cos(pi*(2n+1)k/16), row 0 scaled by 1/sqrt(2).
__device__ __forceinline__ float dctD(int k, int n) {
    const float c[9] = {1.0f, 0.98078528040323043f, 0.92387953251128674f,
                        0.83146961230254524f, 0.70710678118654752f,
                        0.55557023301960218f, 0.38268343236508977f,
                        0.19509032201612825f, 0.0f};
    int m = ((2 * n + 1) * k) & 31;   // cos(m*pi/16), periodic 32
    float s = 1.0f;
    if (m > 16) m = 32 - m;
    if (m > 8) { m = 16 - m; s = -1.0f; }
    float scale = (k == 0) ? 0.35355339059327373f : 0.5f;
    return scale * s * c[m];
}

__device__ __forceinline__ float sigmoidf(float a) {
    return 1.0f / (1.0f + expf(-a));
}

// Workspace layout (floats):
//   feat : [0, 65536)        feat[f*1024 + t],  t = br*32+bc
//   gpart: [65536, 67584)    gpart[wg*64 + c] per-workgroup channel sums
#define WS_FEAT   0
#define WS_GPART  65536

// 32 workgroups x 256 threads; thread (b = tid&31, r = tid>>5) handles row r
// of local block b. Block t = wg*32 + b. No register spills (live ~30 floats).
__global__ __launch_bounds__(256) void dct_kernel(const float* __restrict__ x,
                                                  float* __restrict__ feat,
                                                  float* __restrict__ gpart) {
    __shared__ float Ds[64];
    __shared__ float xs[32][65];   // +1 pad: conflict-free across b
    __shared__ float red[4][64];
    int tid = threadIdx.x;
    if (tid < 64) Ds[tid] = dctD(tid >> 3, tid & 7);
    int b = tid & 31, r = tid >> 5;
    int t = blockIdx.x * 32 + b;
    int br = t >> 5, bc = t & 31;

    // load pixel row r of block b (channel 0 of HWC)
    const float* xrow = x + ((br * 8 + r) * 256 + bc * 8) * 3;
    float px[8];
    #pragma unroll
    for (int l = 0; l < 8; l++) px[l] = xrow[l * 3];
    #pragma unroll
    for (int l = 0; l < 8; l++) xs[b][r * 8 + l] = px[l];
    __syncthreads();

    // tmp row r: tr[l] = sum_k D[r][k] * xs[b][k*8+l]
    float tr[8];
    #pragma unroll
    for (int l = 0; l < 8; l++) tr[l] = 0.f;
    #pragma unroll
    for (int k = 0; k < 8; k++) {
        float d = Ds[r * 8 + k];
        #pragma unroll
        for (int l = 0; l < 8; l++) tr[l] += d * xs[b][k * 8 + l];
    }
    // dct row r: o[j] = sum_l tr[l] * D[j][l];  channel c = r*8+j
    float o[8];
    #pragma unroll
    for (int j = 0; j < 8; j++) {
        float s = 0.f;
        #pragma unroll
        for (int l = 0; l < 8; l++) s += tr[l] * Ds[j * 8 + l];
        o[j] = s;
        feat[(r * 8 + j) * 1024 + t] = s;   // lanes: b consecutive -> coalesced
    }
    __syncthreads();                         // all xs reads done
    #pragma unroll
    for (int j = 0; j < 8; j++) xs[b][r * 8 + j] = o[j];   // xs[b][c] = dct value
    __syncthreads();

    // per-workgroup channel sums (for SE squeeze): c = tid&63, quarter = tid>>6
    int c = tid & 63, qg = tid >> 6;
    float s = 0.f;
    #pragma unroll
    for (int bb = 0; bb < 8; bb++) s += xs[qg * 8 + bb][c];
    red[qg][c] = s;
    __syncthreads();
    if (tid < 64)
        gpart[blockIdx.x * 64 + tid] =
            red[0][tid] + red[1][tid] + red[2][tid] + red[3][tid];
}

// 32 workgroups x 256 threads. Fuses: SE MLP (redundant per wg, reads gpart),
// spatial sigmoid, y = max(f*sc, f*sp), IDCT, write image 0 of d_out.
__global__ __launch_bounds__(256) void idct_kernel(const float* __restrict__ feat,
                                                   const float* __restrict__ gpart,
                                                   const float* __restrict__ fc1_w,
                                                   const float* __restrict__ fc1_b,
                                                   const float* __restrict__ fc2_w,
                                                   const float* __restrict__ fc2_b,
                                                   const float* __restrict__ sse_w,
                                                   const float* __restrict__ sse_b,
                                                   float* __restrict__ out0) {
    __shared__ float Ds[64], sw[64], sq[64], sc[64], h[32], spat[32];
    __shared__ float redp[8][33];
    __shared__ float tmls[32][65];
    int tid = threadIdx.x;
    if (tid < 64) {
        Ds[tid] = dctD(tid >> 3, tid & 7);
        sw[tid] = sse_w[tid];
        float s = 0.f;
        #pragma unroll
        for (int w = 0; w < 32; w++) s += gpart[w * 64 + tid];
        sq[tid] = s * (1.0f / 1024.0f);
    }
    __syncthreads();
    if (tid < 32) {
        float a = fc1_b[tid];
        #pragma unroll 8
        for (int cc = 0; cc < 64; cc++) a += sq[cc] * fc1_w[tid * 64 + cc];
        h[tid] = fmaxf(a, 0.f);
    }
    __syncthreads();
    if (tid < 64) {
        float a = fc2_b[tid];
        #pragma unroll 8
        for (int rr = 0; rr < 32; rr++) a += h[rr] * fc2_w[tid * 32 + rr];
        sc[tid] = sigmoidf(a);
    }

    int b = tid & 31, r = tid >> 5;
    int t = blockIdx.x * 32 + b;

    // load feat row r of block b (coalesced: lanes span consecutive t)
    float gr[8];
    #pragma unroll
    for (int l = 0; l < 8; l++) gr[l] = feat[(r * 8 + l) * 1024 + t];
    // spatial dot partial for this row
    float sp = 0.f;
    #pragma unroll
    for (int l = 0; l < 8; l++) sp += sw[r * 8 + l] * gr[l];
    redp[r][b] = sp;
    __syncthreads();    // covers sc + redp
    if (tid < 32) {
        float a = sse_b[0];
        #pragma unroll
        for (int rr = 0; rr < 8; rr++) a += redp[rr][tid];
        spat[tid] = sigmoidf(a);
    }
    __syncthreads();

    // y row r and first-pass IDCT row: tm[j] = sum_l y[l] * D[l][j]
    float spb = spat[b];
    float tm[8];
    #pragma unroll
    for (int j = 0; j < 8; j++) tm[j] = 0.f;
    #pragma unroll
    for (int l = 0; l < 8; l++) {
        float v = gr[l];
        float y = fmaxf(v * sc[r * 8 + l], v * spb);  // feat may be negative
        #pragma unroll
        for (int j = 0; j < 8; j++) tm[j] += y * Ds[l * 8 + j];
    }
    #pragma unroll
    for (int j = 0; j < 8; j++) tmls[b][r * 8 + j] = tm[j];
    __syncthreads();

    // out row r: o[j] = sum_k D[k][r] * tm[k][j]
    float o[8];
    #pragma unroll
    for (int j = 0; j < 8; j++) o[j] = 0.f;
    #pragma unroll
    for (int k = 0; k < 8; k++) {
        float d = Ds[k * 8 + r];
        #pragma unroll
        for (int j = 0; j < 8; j++) o[j] += d * tmls[b][k * 8 + j];
    }
    int br = t >> 5, bc = t & 31;
    float4* dst = (float4*)(out0 + (br * 8 + r) * 256 + bc * 8);
    dst[0] = make_float4(o[0], o[1], o[2], o[3]);
    dst[1] = make_float4(o[4], o[5], o[6], o[7]);
}

// Replicate image 0 (first 65536 floats of out) into images 1..191.
__global__ __launch_bounds__(256) void bcast_kernel(float* __restrict__ out, int total4) {
    const float4* s = (const float4*)out;
    float4* d = (float4*)out;
    int stride = gridDim.x * blockDim.x;
    for (int idx = blockIdx.x * blockDim.x + threadIdx.x + 16384; idx < total4; idx += stride) {
        d[idx] = s[idx & 16383];   // 16384 float4 per 256x256 image
    }
}

extern "C" void kernel_launch(void* const* d_in, const int* in_sizes, int n_in,
                              void* d_out, int out_size, void* d_ws, size_t ws_size,
                              hipStream_t stream) {
    const float* x     = (const float*)d_in[0];
    const float* fc1_w = (const float*)d_in[1];
    const float* fc1_b = (const float*)d_in[2];
    const float* fc2_w = (const float*)d_in[3];
    const float* fc2_b = (const float*)d_in[4];
    const float* sse_w = (const float*)d_in[5];
    const float* sse_b = (const float*)d_in[6];
    float* ws = (float*)d_ws;
    float* feat  = ws + WS_FEAT;
    float* gpart = ws + WS_GPART;
    float* out = (float*)d_out;

    dct_kernel<<<32, 256, 0, stream>>>(x, feat, gpart);
    idct_kernel<<<32, 256, 0, stream>>>(feat, gpart, fc1_w, fc1_b, fc2_w, fc2_b,
                                        sse_w, sse_b, out);
    int total4 = out_size / 4;
    bcast_kernel<<<3072, 256, 0, stream>>>(out, total4);
}

// Round 3
// 93.071 us; speedup vs baseline: 1.4723x; 1.0017x over previous
//
#include <hip/hip_runtime.h>
#include <hip/hip_bf16.h>
#include <math.h>

// D[k][n] = 0.5*cos(pi*(2n+1)k/16), row 0 scaled by 1/sqrt(2).
__device__ __forceinline__ float dctD(int k, int n) {
    const float c[9] = {1.0f, 0.98078528040323043f, 0.92387953251128674f,
                        0.83146961230254524f, 0.70710678118654752f,
                        0.55557023301960218f, 0.38268343236508977f,
                        0.19509032201612825f, 0.0f};
    int m = ((2 * n + 1) * k) & 31;   // cos(m*pi/16), periodic 32
    float s = 1.0f;
    if (m > 16) m = 32 - m;
    if (m > 8) { m = 16 - m; s = -1.0f; }
    float scale = (k == 0) ? 0.35355339059327373f : 0.5f;
    return scale * s * c[m];
}

__device__ __forceinline__ float sigmoidf(float a) {
    return 1.0f / (1.0f + expf(-a));
}

// Workspace layout (floats):
//   feat : [0, 65536)        feat[f*1024 + t],  t = br*32+bc
//   gpart: [65536, 67584)    gpart[wg*64 + c] per-workgroup channel sums
#define WS_FEAT   0
#define WS_GPART  65536

// 32 workgroups x 256 threads; thread (b = tid&31, r = tid>>5) handles row r
// of local block b. Block t = wg*32 + b.
__global__ __launch_bounds__(256) void dct_kernel(const float* __restrict__ x,
                                                  float* __restrict__ feat,
                                                  float* __restrict__ gpart) {
    __shared__ float Ds[64];
    __shared__ float xs[32][65];   // +1 pad: conflict-free across b
    __shared__ float red[4][64];
    int tid = threadIdx.x;
    if (tid < 64) Ds[tid] = dctD(tid >> 3, tid & 7);
    int b = tid & 31, r = tid >> 5;
    int t = blockIdx.x * 32 + b;
    int br = t >> 5, bc = t & 31;

    // load pixel row r of block b: 8 HWC pixels = 24 floats = 6 float4, contiguous
    // per lane -> wave covers contiguous 3 KB. Extract channel 0 (every 3rd).
    const float4* xrow4 = (const float4*)(x + ((br * 8 + r) * 256 + bc * 8) * 3);
    float4 v0 = xrow4[0], v1 = xrow4[1], v2 = xrow4[2];
    float4 v3 = xrow4[3], v4 = xrow4[4], v5 = xrow4[5];
    xs[b][r * 8 + 0] = v0.x;  xs[b][r * 8 + 1] = v0.w;
    xs[b][r * 8 + 2] = v1.z;  xs[b][r * 8 + 3] = v2.y;
    xs[b][r * 8 + 4] = v3.x;  xs[b][r * 8 + 5] = v3.w;
    xs[b][r * 8 + 6] = v4.z;  xs[b][r * 8 + 7] = v5.y;
    __syncthreads();

    // tmp row r: tr[l] = sum_k D[r][k] * xs[b][k*8+l]
    float tr[8];
    #pragma unroll
    for (int l = 0; l < 8; l++) tr[l] = 0.f;
    #pragma unroll
    for (int k = 0; k < 8; k++) {
        float d = Ds[r * 8 + k];
        #pragma unroll
        for (int l = 0; l < 8; l++) tr[l] += d * xs[b][k * 8 + l];
    }
    // dct row r: o[j] = sum_l tr[l] * D[j][l];  channel c = r*8+j
    float o[8];
    #pragma unroll
    for (int j = 0; j < 8; j++) {
        float s = 0.f;
        #pragma unroll
        for (int l = 0; l < 8; l++) s += tr[l] * Ds[j * 8 + l];
        o[j] = s;
        feat[(r * 8 + j) * 1024 + t] = s;   // lanes: b consecutive -> coalesced
    }
    __syncthreads();                         // all xs reads done
    #pragma unroll
    for (int j = 0; j < 8; j++) xs[b][r * 8 + j] = o[j];   // xs[b][c] = dct value
    __syncthreads();

    // per-workgroup channel sums (for SE squeeze)
    int c = tid & 63, qg = tid >> 6;
    float s = 0.f;
    #pragma unroll
    for (int bb = 0; bb < 8; bb++) s += xs[qg * 8 + bb][c];
    red[qg][c] = s;
    __syncthreads();
    if (tid < 64)
        gpart[blockIdx.x * 64 + tid] =
            red[0][tid] + red[1][tid] + red[2][tid] + red[3][tid];
}

// 1024 workgroups x 256 threads: wg = ig*32 + tg.
//   tg (0..31): block group, handles blocks t = tg*32 + b (b = tid&31)
//   ig (0..31): image group, writes images ig*6 .. ig*6+5
// Each wg redundantly computes SE MLP + spatial + IDCT for its 32 blocks
// (compute is ~2 KFLOP/thread — noise), then fans the 8 KB tile out to its
// 6 images with perfectly coalesced float4 stores. This overlaps the IDCT
// with the 50 MB output write at full-grid write bandwidth.
__global__ __launch_bounds__(256) void idct_bcast_kernel(const float* __restrict__ feat,
                                                         const float* __restrict__ gpart,
                                                         const float* __restrict__ fc1_w,
                                                         const float* __restrict__ fc1_b,
                                                         const float* __restrict__ fc2_w,
                                                         const float* __restrict__ fc2_b,
                                                         const float* __restrict__ sse_w,
                                                         const float* __restrict__ sse_b,
                                                         float* __restrict__ out,
                                                         int nimg) {
    __shared__ float Ds[64], sw[64], sq[64], sc[64], h[32], spat[32];
    __shared__ float redp[8][33];
    __shared__ float tmls[32][65];
    __shared__ float otile[2048];   // [8 rows][256 cols] of this tg's out stripe
    int tid = threadIdx.x;
    int tg = blockIdx.x & 31;
    int ig = blockIdx.x >> 5;

    if (tid < 64) {
        Ds[tid] = dctD(tid >> 3, tid & 7);
        sw[tid] = sse_w[tid];
        float s = 0.f;
        #pragma unroll
        for (int w = 0; w < 32; w++) s += gpart[w * 64 + tid];
        sq[tid] = s * (1.0f / 1024.0f);
    }
    __syncthreads();
    if (tid < 32) {
        float a = fc1_b[tid];
        #pragma unroll 8
        for (int cc = 0; cc < 64; cc++) a += sq[cc] * fc1_w[tid * 64 + cc];
        h[tid] = fmaxf(a, 0.f);
    }
    __syncthreads();
    if (tid < 64) {
        float a = fc2_b[tid];
        #pragma unroll 8
        for (int rr = 0; rr < 32; rr++) a += h[rr] * fc2_w[tid * 32 + rr];
        sc[tid] = sigmoidf(a);
    }

    int b = tid & 31, r = tid >> 5;
    int t = tg * 32 + b;

    // load feat row r of block b (coalesced: lanes span consecutive t)
    float gr[8];
    #pragma unroll
    for (int l = 0; l < 8; l++) gr[l] = feat[(r * 8 + l) * 1024 + t];
    // spatial dot partial for this row
    float sp = 0.f;
    #pragma unroll
    for (int l = 0; l < 8; l++) sp += sw[r * 8 + l] * gr[l];
    redp[r][b] = sp;
    __syncthreads();    // covers sc + redp
    if (tid < 32) {
        float a = sse_b[0];
        #pragma unroll
        for (int rr = 0; rr < 8; rr++) a += redp[rr][tid];
        spat[tid] = sigmoidf(a);
    }
    __syncthreads();

    // y row r and first-pass IDCT: tm[j] = sum_l y[l] * D[l][j]
    float spb = spat[b];
    float tm[8];
    #pragma unroll
    for (int j = 0; j < 8; j++) tm[j] = 0.f;
    #pragma unroll
    for (int l = 0; l < 8; l++) {
        float v = gr[l];
        float y = fmaxf(v * sc[r * 8 + l], v * spb);  // feat may be negative
        #pragma unroll
        for (int j = 0; j < 8; j++) tm[j] += y * Ds[l * 8 + j];
    }
    #pragma unroll
    for (int j = 0; j < 8; j++) tmls[b][r * 8 + j] = tm[j];
    __syncthreads();

    // out row r of block b: o[j] = sum_k D[k][r] * tm[k][j]
    float o[8];
    #pragma unroll
    for (int j = 0; j < 8; j++) o[j] = 0.f;
    #pragma unroll
    for (int k = 0; k < 8; k++) {
        float d = Ds[k * 8 + r];
        #pragma unroll
        for (int j = 0; j < 8; j++) o[j] += d * tmls[b][k * 8 + j];
    }
    // stage into otile: block b occupies cols b*8..b*8+7 of local row r
    #pragma unroll
    for (int j = 0; j < 8; j++) otile[r * 256 + b * 8 + j] = o[j];
    __syncthreads();

    // fan out: this tg's stripe = rows tg*8..tg*8+7 = 2048 floats = 512 float4,
    // thread w writes float4 w and w+256 -> perfectly contiguous per wave.
    const float4* src = (const float4*)otile;
    float4 w0 = src[tid];
    float4 w1 = src[tid + 256];
    #pragma unroll
    for (int m = 0; m < 6; m++) {
        int img = ig * 6 + m;
        if (img < nimg) {
            float4* dst = (float4*)(out + (size_t)img * 65536 + tg * 2048);
            dst[tid] = w0;
            dst[tid + 256] = w1;
        }
    }
}

extern "C" void kernel_launch(void* const* d_in, const int* in_sizes, int n_in,
                              void* d_out, int out_size, void* d_ws, size_t ws_size,
                              hipStream_t stream) {
    const float* x     = (const float*)d_in[0];
    const float* fc1_w = (const float*)d_in[1];
    const float* fc1_b = (const float*)d_in[2];
    const float* fc2_w = (const float*)d_in[3];
    const float* fc2_b = (const float*)d_in[4];
    const float* sse_w = (const float*)d_in[5];
    const float* sse_b = (const float*)d_in[6];
    float* ws = (float*)d_ws;
    float* feat  = ws + WS_FEAT;
    float* gpart = ws + WS_GPART;
    float* out = (float*)d_out;
    int nimg = out_size / 65536;   // 192 for bs=64

    dct_kernel<<<32, 256, 0, stream>>>(x, feat, gpart);
    idct_bcast_kernel<<<1024, 256, 0, stream>>>(feat, gpart, fc1_w, fc1_b,
                                                fc2_w, fc2_b, sse_w, sse_b,
                                                out, nimg);
}